// Round 6
// baseline (262.168 us; speedup 1.0000x reference)
//
#include <hip/hip_runtime.h>
#include <hip/hip_bf16.h>
#include <hip/hip_cooperative_groups.h>
#include <math.h>

// Problem constants
#define Bz    4
#define Cch   192
#define Nn    4096
#define BN    16384      // Bz*Nn
#define Ecnt  262144     // Bz*Nn*16
#define COUT  384
#define CAP   64         // max degree capacity (random 262144->16384 bins: max ~34)
#define MSTR  200        // Ms/Xs row stride in shorts (400 B: bank 4r%32 -> 2-way free)
#define NBLK  512        // grid (co-resident: >=2 blocks/CU * 256 CU)
#define NTHR  512        // 8 waves/block -> 16 waves/CU

typedef __attribute__((ext_vector_type(8))) short short8;
typedef __attribute__((ext_vector_type(4))) float floatx4;

__device__ __forceinline__ float b2f(unsigned short u) {
    union { unsigned int i; float f; } z; z.i = ((unsigned int)u) << 16; return z.f;
}
__device__ __forceinline__ unsigned short f2b(float f) {
    __hip_bfloat16 h = __float2bfloat16(f);
    return *(unsigned short*)&h;
}

#define RED8(mm, FLD) do {                                                    \
    float a_ = fmaxf(fmaxf(b2f(v[0].FLD), b2f(v[1].FLD)),                     \
                     fmaxf(b2f(v[2].FLD), b2f(v[3].FLD)));                    \
    float b_ = fmaxf(fmaxf(b2f(v[4].FLD), b2f(v[5].FLD)),                     \
                     fmaxf(b2f(v[6].FLD), b2f(v[7].FLD)));                    \
    mm = fmaxf(mm, fmaxf(a_, b_)); } while (0)

// ---------------------------------------------------------------------------
// Shared phase bodies (used by both the cooperative mono kernel and the
// 3-kernel fallback). Algebra: out = Wx.x + Wa.(M-x) = Wxa.x + Wa.M',
// M' = (d>0 ? max_{nbr} x : x).

__device__ __forceinline__ void p0_body(
    int bid, int tid, void* smem,
    const float* __restrict__ x, const unsigned int* __restrict__ ew,
    const float* __restrict__ W, __hip_bfloat16* __restrict__ xb,
    __hip_bfloat16* __restrict__ Wxa, __hip_bfloat16* __restrict__ Wa,
    int* __restrict__ deg, int* __restrict__ flag)
{
    float (*tr)[33] = (float(*)[33])smem;
    int tx = tid & 31, ty = tid >> 5;        // ty 0..15
    for (int r = bid; r < 3072; r += NBLK) { // exactly 6 tiles/block
        int b = r / 768, rr = r - b * 768;
        int c0 = (rr >> 7) * 32, n0 = (rr & 127) * 32;
        for (int i = ty; i < 32; i += 16)
            tr[i][tx] = x[((size_t)(b * Cch + c0 + i)) * Nn + n0 + tx];
        __syncthreads();
        for (int i = ty; i < 32; i += 16)
            xb[((size_t)(b * Nn + n0 + i)) * Cch + c0 + tx] =
                __float2bfloat16(tr[tx][i]);
        __syncthreads();
    }
    int idx = bid * NTHR + tid;              // [0, 262144)
    if (idx < COUT * Cch) {
        int o = idx / Cch, c = idx - o * Cch;
        float wx = W[o * 2 * Cch + 2 * c];
        float wa = W[o * 2 * Cch + 2 * c + 1];
        Wxa[idx] = __float2bfloat16(wx - wa);   // fp32 difference, one rounding
        Wa[idx]  = __float2bfloat16(wa);
    }
    if (idx < BN) deg[idx] = 0;
    if (bid == 0) {                          // int64 detect: odd words all 0
        if (tid == 0) *flag = 1;
        __syncthreads();
        if (ew[2 * tid + 1] != 0u) atomicAnd(flag, 0);
    }
}

__device__ __forceinline__ void p1_body(
    int bid, int tid, const unsigned int* __restrict__ ew,
    const int* __restrict__ flag, int* __restrict__ deg,
    int* __restrict__ slots)
{
    int t = bid * NTHR + tid;                // [0, Ecnt), 1 edge/thread
    int d0, s0;
    if (*flag) {    // int64: dst e -> word 2e; src e -> word 2*Ecnt + 2e
        d0 = (int)ew[2 * t];
        s0 = (int)ew[2 * Ecnt + 2 * t];
    } else {        // int32
        d0 = (int)ew[t];
        s0 = (int)ew[Ecnt + t];
    }
    int p0 = atomicAdd(&deg[d0], 1);
    if (p0 < CAP) slots[(d0 << 6) + p0] = s0;
}

__device__ __forceinline__ void p2_body(
    int bid, int tid, void* smem,
    const int* __restrict__ deg, const int* __restrict__ slots,
    const __hip_bfloat16* __restrict__ xb,
    const __hip_bfloat16* __restrict__ Wxa, const __hip_bfloat16* __restrict__ Wa,
    const float* __restrict__ bias, float* __restrict__ out)
{
    unsigned short* Xs = (unsigned short*)smem;                       // [32][MSTR]
    unsigned short* Ms = (unsigned short*)((char*)smem + 32 * MSTR * 2);
    int lane = tid & 63, wave = tid >> 6;    // wave 0..7
    int quad = lane >> 4, lrow = lane & 15;
    int node0 = bid * 32;
    const unsigned short* xbu = (const unsigned short*)xb;
    int act = lane < 48;
    int cb = lane * 4;

    // Phase A: gather M' (and stage x rows), 4 nodes per wave
    for (int nl = wave * 4; nl < wave * 4 + 4; nl++) {
        int node = node0 + nl;
        int d = deg[node]; if (d > CAP) d = CAP;
        d = __builtin_amdgcn_readfirstlane(d);   // wave-uniform loop bound
        int nbrval = 0;
        if (lane < d) nbrval = slots[(node << 6) + lane];
        ushort4 xv = {0, 0, 0, 0};
        if (act) xv = *(const ushort4*)&xbu[node * Cch + cb];
        float m0 = -INFINITY, m1 = -INFINITY, m2 = -INFINITY, m3 = -INFINITY;
        int k = 0;
        for (; k + 8 <= d; k += 8) {
            int s[8];
#pragma unroll
            for (int u = 0; u < 8; u++) s[u] = __builtin_amdgcn_readlane(nbrval, k + u);
            if (act) {
                ushort4 v[8];
#pragma unroll
                for (int u = 0; u < 8; u++) v[u] = *(const ushort4*)&xbu[s[u] * Cch + cb];
                RED8(m0, x); RED8(m1, y); RED8(m2, z); RED8(m3, w);
            }
        }
        if (k + 4 <= d) {
            int s0 = __builtin_amdgcn_readlane(nbrval, k);
            int s1 = __builtin_amdgcn_readlane(nbrval, k + 1);
            int s2 = __builtin_amdgcn_readlane(nbrval, k + 2);
            int s3 = __builtin_amdgcn_readlane(nbrval, k + 3);
            if (act) {
                ushort4 v0 = *(const ushort4*)&xbu[s0 * Cch + cb];
                ushort4 v1 = *(const ushort4*)&xbu[s1 * Cch + cb];
                ushort4 v2 = *(const ushort4*)&xbu[s2 * Cch + cb];
                ushort4 v3 = *(const ushort4*)&xbu[s3 * Cch + cb];
                m0 = fmaxf(m0, fmaxf(fmaxf(b2f(v0.x), b2f(v1.x)), fmaxf(b2f(v2.x), b2f(v3.x))));
                m1 = fmaxf(m1, fmaxf(fmaxf(b2f(v0.y), b2f(v1.y)), fmaxf(b2f(v2.y), b2f(v3.y))));
                m2 = fmaxf(m2, fmaxf(fmaxf(b2f(v0.z), b2f(v1.z)), fmaxf(b2f(v2.z), b2f(v3.z))));
                m3 = fmaxf(m3, fmaxf(fmaxf(b2f(v0.w), b2f(v1.w)), fmaxf(b2f(v2.w), b2f(v3.w))));
            }
            k += 4;
        }
        for (; k < d; k++) {
            int s = __builtin_amdgcn_readlane(nbrval, k);
            if (act) {
                ushort4 v = *(const ushort4*)&xbu[s * Cch + cb];
                m0 = fmaxf(m0, b2f(v.x)); m1 = fmaxf(m1, b2f(v.y));
                m2 = fmaxf(m2, b2f(v.z)); m3 = fmaxf(m3, b2f(v.w));
            }
        }
        if (act) {
            *(ushort4*)&Xs[nl * MSTR + cb] = xv;
            ushort4 o4;
            if (d > 0) {                      // wave-uniform branch
                o4.x = f2b(m0); o4.y = f2b(m1); o4.z = f2b(m2); o4.w = f2b(m3);
            } else {                          // empty segment: M' = x (cancels)
                o4 = xv;
            }
            *(ushort4*)&Ms[nl * MSTR + cb] = o4;
        }
    }
    __syncthreads();

    // Phase B: K-loop, no barriers. Wave covers o in [wave*48, wave*48+48).
    // W fragments straight from global (288 KB, L2-resident, all blocks share).
    floatx4 acc[2][3] = {};
    const unsigned short* Wx16 = (const unsigned short*)Wxa;
    const unsigned short* Wa16 = (const unsigned short*)Wa;
    for (int s = 0; s < 6; s++) {
        int kk = s * 32 + quad * 8;
        short8 af[2], bf[3];
#pragma unroll
        for (int i = 0; i < 2; i++)
            af[i] = *(const short8*)&Xs[(i * 16 + lrow) * MSTR + kk];
#pragma unroll
        for (int j = 0; j < 3; j++)
            bf[j] = *(const short8*)&Wx16[(size_t)(wave * 48 + j * 16 + lrow) * Cch + kk];
#pragma unroll
        for (int i = 0; i < 2; i++)
#pragma unroll
            for (int j = 0; j < 3; j++)
                acc[i][j] = __builtin_amdgcn_mfma_f32_16x16x32_bf16(bf[j], af[i], acc[i][j], 0, 0, 0);
    }
    for (int s = 0; s < 6; s++) {
        int kk = s * 32 + quad * 8;
        short8 af[2], bf[3];
#pragma unroll
        for (int i = 0; i < 2; i++)
            af[i] = *(const short8*)&Ms[(i * 16 + lrow) * MSTR + kk];
#pragma unroll
        for (int j = 0; j < 3; j++)
            bf[j] = *(const short8*)&Wa16[(size_t)(wave * 48 + j * 16 + lrow) * Cch + kk];
#pragma unroll
        for (int i = 0; i < 2; i++)
#pragma unroll
            for (int j = 0; j < 3; j++)
                acc[i][j] = __builtin_amdgcn_mfma_f32_16x16x32_bf16(bf[j], af[i], acc[i][j], 0, 0, 0);
    }

    // Epilogue. D layout: col(lane&15)=node, row(quad*4+r)=o
#pragma unroll
    for (int i = 0; i < 2; i++) {
        int node = node0 + i * 16 + lrow;
        int b = node >> 12, n = node & 4095;
#pragma unroll
        for (int j = 0; j < 3; j++) {
            int ob = wave * 48 + j * 16 + quad * 4;
#pragma unroll
            for (int r = 0; r < 4; r++) {
                int o = ob + r;
                float v = acc[i][j][r] + bias[o];
                out[((size_t)(b * COUT + o)) * Nn + n] = fmaxf(v, 0.0f);
            }
        }
    }
}

// ---------------------------------------------------------------------------
// Cooperative mono kernel: P0 -> grid.sync -> P1 -> grid.sync -> P2.
__global__ __launch_bounds__(NTHR, 4) void mono_kernel(
    const float* __restrict__ x, const unsigned int* __restrict__ ew,
    const float* __restrict__ W, const float* __restrict__ bias,
    __hip_bfloat16* __restrict__ xb, __hip_bfloat16* __restrict__ Wxa,
    __hip_bfloat16* __restrict__ Wa, int* __restrict__ deg,
    int* __restrict__ slots, int* __restrict__ flag,
    float* __restrict__ out)
{
    __shared__ __align__(16) char smem[2 * 32 * MSTR * 2];   // 25600 B
    int tid = threadIdx.x, bid = blockIdx.x;
    p0_body(bid, tid, smem, x, ew, W, xb, Wxa, Wa, deg, flag);
    cooperative_groups::this_grid().sync();
    p1_body(bid, tid, ew, flag, deg, slots);
    cooperative_groups::this_grid().sync();
    p2_body(bid, tid, smem, deg, slots, xb, Wxa, Wa, bias, out);
}

// Fallback path: same phases as 3 ordinary kernels (stream-ordered).
__global__ __launch_bounds__(NTHR) void p0_kernel(
    const float* __restrict__ x, const unsigned int* __restrict__ ew,
    const float* __restrict__ W, __hip_bfloat16* __restrict__ xb,
    __hip_bfloat16* __restrict__ Wxa, __hip_bfloat16* __restrict__ Wa,
    int* __restrict__ deg, int* __restrict__ flag)
{
    __shared__ __align__(16) char smem[4224];
    p0_body(blockIdx.x, threadIdx.x, smem, x, ew, W, xb, Wxa, Wa, deg, flag);
}
__global__ __launch_bounds__(NTHR) void p1_kernel(
    const unsigned int* __restrict__ ew, const int* __restrict__ flag,
    int* __restrict__ deg, int* __restrict__ slots)
{
    p1_body(blockIdx.x, threadIdx.x, ew, flag, deg, slots);
}
__global__ __launch_bounds__(NTHR, 4) void p2_kernel(
    const int* __restrict__ deg, const int* __restrict__ slots,
    const __hip_bfloat16* __restrict__ xb,
    const __hip_bfloat16* __restrict__ Wxa, const __hip_bfloat16* __restrict__ Wa,
    const float* __restrict__ bias, float* __restrict__ out)
{
    __shared__ __align__(16) char smem[2 * 32 * MSTR * 2];
    p2_body(blockIdx.x, threadIdx.x, smem, deg, slots, xb, Wxa, Wa, bias, out);
}

// ---------------------------------------------------------------------------
extern "C" void kernel_launch(void* const* d_in, const int* in_sizes, int n_in,
                              void* d_out, int out_size, void* d_ws, size_t ws_size,
                              hipStream_t stream) {
    const float* x    = (const float*)d_in[0];
    const unsigned int* ew = (const unsigned int*)d_in[1];
    const float* W    = (const float*)d_in[2];
    const float* bias = (const float*)d_in[3];
    float* out        = (float*)d_out;

    char* ws = (char*)d_ws;
    __hip_bfloat16* xb   = (__hip_bfloat16*)ws;                       // 6291456 B
    __hip_bfloat16* Wxa  = (__hip_bfloat16*)(ws + 12582912);          // 147456 B
    __hip_bfloat16* Wa   = (__hip_bfloat16*)(ws + 12730368);          // 147456 B
    int* deg   = (int*)(ws + 12877824);                               // 65536 B
    int* slots = (int*)(ws + 12943360);                               // 4194304 B
    int* flag  = (int*)(ws + 17137664);                               // 4 B

    void* args[] = { (void*)&x, (void*)&ew, (void*)&W, (void*)&bias,
                     (void*)&xb, (void*)&Wxa, (void*)&Wa, (void*)&deg,
                     (void*)&slots, (void*)&flag, (void*)&out };
    hipError_t err = hipLaunchCooperativeKernel((const void*)mono_kernel,
                                                dim3(NBLK), dim3(NTHR),
                                                args, 0, stream);
    if (err != hipSuccess) {
        // Graph-capture or co-residency rejection: stream-ordered fallback.
        p0_kernel<<<NBLK, NTHR, 0, stream>>>(x, ew, W, xb, Wxa, Wa, deg, flag);
        p1_kernel<<<NBLK, NTHR, 0, stream>>>(ew, flag, deg, slots);
        p2_kernel<<<NBLK, NTHR, 0, stream>>>(deg, slots, xb, Wxa, Wa, bias, out);
    }
}

// Round 7
// 123.155 us; speedup vs baseline: 2.1288x; 2.1288x over previous
//
#include <hip/hip_runtime.h>
#include <hip/hip_bf16.h>
#include <math.h>

// Problem constants
#define Bz    4
#define Cch   192
#define Nn    4096
#define BN    16384      // Bz*Nn
#define Ecnt  262144     // Bz*Nn*16
#define COUT  384
#define CAP   64         // max degree capacity (random 262144->16384 bins: max ~34)
#define MSTR  200        // Ms/Xs row stride in shorts (400 B)

typedef __attribute__((ext_vector_type(8))) short short8;
typedef __attribute__((ext_vector_type(4))) float floatx4;

__device__ __forceinline__ float b2f(unsigned short u) {
    union { unsigned int i; float f; } z; z.i = ((unsigned int)u) << 16; return z.f;
}
__device__ __forceinline__ unsigned short f2b(float f) {
    __hip_bfloat16 h = __float2bfloat16(f);
    return *(unsigned short*)&h;
}

#define RED8(mm, FLD) do {                                                    \
    float a_ = fmaxf(fmaxf(b2f(v[0].FLD), b2f(v[1].FLD)),                     \
                     fmaxf(b2f(v[2].FLD), b2f(v[3].FLD)));                    \
    float b_ = fmaxf(fmaxf(b2f(v[4].FLD), b2f(v[5].FLD)),                     \
                     fmaxf(b2f(v[6].FLD), b2f(v[7].FLD)));                    \
    mm = fmaxf(mm, fmaxf(a_, b_)); } while (0)

// ---------------------------------------------------------------------------
// Fused prep (R2-proven): [0,3072) transpose x->xb bf16; [3072,3360) W ->
// Wxa=bf16(Wx-Wa), Wa=bf16(Wa); [3360,3424) zero deg; [3424] int64 detect.
// Algebra: out = Wx·x + Wa·(M-x) = (Wx-Wa)·x + Wa·M', M' = (d>0 ? max : x).
__global__ __launch_bounds__(256) void prep_kernel(
    const float* __restrict__ x, const unsigned int* __restrict__ ew,
    const float* __restrict__ W, __hip_bfloat16* __restrict__ xb,
    __hip_bfloat16* __restrict__ Wxa, __hip_bfloat16* __restrict__ Wa,
    int* __restrict__ deg, int* __restrict__ flag) {
    int bid = blockIdx.x;
    if (bid < 3072) {
        __shared__ float tile[32][33];
        int b = bid / 768;
        int r = bid - b * 768;
        int c0 = (r >> 7) * 32;         // 6 c-tiles
        int n0 = (r & 127) * 32;        // 128 n-tiles
        int tx = threadIdx.x & 31, ty = threadIdx.x >> 5;
        for (int i = ty; i < 32; i += 8)
            tile[i][tx] = x[((size_t)(b * Cch + c0 + i)) * Nn + n0 + tx];
        __syncthreads();
        for (int i = ty; i < 32; i += 8)
            xb[((size_t)(b * Nn + n0 + i)) * Cch + c0 + tx] =
                __float2bfloat16(tile[tx][i]);
    } else if (bid < 3360) {
        int i = (bid - 3072) * 256 + threadIdx.x;   // exactly COUT*Cch = 73728
        int o = i / Cch, c = i - o * Cch;
        float wx = W[o * 2 * Cch + 2 * c];
        float wa = W[o * 2 * Cch + 2 * c + 1];
        Wxa[i] = __float2bfloat16(wx - wa);          // fp32 difference, one rounding
        Wa[i]  = __float2bfloat16(wa);
    } else if (bid < 3424) {
        deg[(bid - 3360) * 256 + threadIdx.x] = 0;  // exactly BN = 16384
    } else {
        __shared__ int s;
        if (threadIdx.x == 0) s = 1;
        __syncthreads();
        if (ew[2 * threadIdx.x + 1] != 0u) atomicAnd(&s, 0);
        __syncthreads();
        if (threadIdx.x == 0) *flag = s;
    }
}

// ---------------------------------------------------------------------------
// Count degree + place src into fixed-capacity slot table. 2 edges/thread.
// (R2-proven vectorized loads.)
__global__ __launch_bounds__(256) void fill_kernel(
    const int* __restrict__ ew, const int* __restrict__ flag,
    int* __restrict__ deg, int* __restrict__ slots) {
    int t = blockIdx.x * 256 + threadIdx.x;   // [0, Ecnt/2)
    int d0, d1, s0, s1;
    if (*flag) {    // int64: dst e -> word 2e; src e -> word 2*Ecnt + 2e
        int4 dv = *(const int4*)&ew[4 * t];
        int4 sv = *(const int4*)&ew[2 * Ecnt + 4 * t];
        d0 = dv.x; d1 = dv.z; s0 = sv.x; s1 = sv.z;
    } else {        // int32
        int2 dv = *(const int2*)&ew[2 * t];
        int2 sv = *(const int2*)&ew[Ecnt + 2 * t];
        d0 = dv.x; d1 = dv.y; s0 = sv.x; s1 = sv.y;
    }
    int p0 = atomicAdd(&deg[d0], 1); if (p0 < CAP) slots[(d0 << 6) + p0] = s0;
    int p1 = atomicAdd(&deg[d1], 1); if (p1 < CAP) slots[(d1 << 6) + p1] = s1;
}

// ---------------------------------------------------------------------------
// Fused gather+GEMM (verified inside R6 mono). Block = 32 nodes x 384 outs,
// 512 threads (8 waves -> 16 waves/CU with 2 blocks/CU).
// Phase A: gather M'[32][192] + x rows into LDS, 4 nodes/wave.
// Phase B: C = [x|M'] . [Wxa|Wa]^T; W fragments from global (288 KB,
//          L2-resident, shared by all blocks), one-step software prefetch;
//          no K-loop barriers. Accum order: seg0 s=0..5 then seg1 (same as R2).
#define MFMA6()                                                                \
    acc00 = __builtin_amdgcn_mfma_f32_16x16x32_bf16(b0, af0, acc00, 0, 0, 0);  \
    acc10 = __builtin_amdgcn_mfma_f32_16x16x32_bf16(b0, af1, acc10, 0, 0, 0);  \
    acc01 = __builtin_amdgcn_mfma_f32_16x16x32_bf16(b1, af0, acc01, 0, 0, 0);  \
    acc11 = __builtin_amdgcn_mfma_f32_16x16x32_bf16(b1, af1, acc11, 0, 0, 0);  \
    acc02 = __builtin_amdgcn_mfma_f32_16x16x32_bf16(b2, af0, acc02, 0, 0, 0);  \
    acc12 = __builtin_amdgcn_mfma_f32_16x16x32_bf16(b2, af1, acc12, 0, 0, 0)

__global__ __launch_bounds__(512, 4) void p2_kernel(
    const int* __restrict__ deg, const int* __restrict__ slots,
    const __hip_bfloat16* __restrict__ xb,
    const __hip_bfloat16* __restrict__ Wxa, const __hip_bfloat16* __restrict__ Wa,
    const float* __restrict__ bias, float* __restrict__ out)
{
    __shared__ __align__(16) unsigned short Xs[32 * MSTR];
    __shared__ __align__(16) unsigned short Ms[32 * MSTR];
    int tid = threadIdx.x, bid = blockIdx.x;
    int lane = tid & 63, wave = tid >> 6;    // wave 0..7
    int quad = lane >> 4, lrow = lane & 15;
    int node0 = bid * 32;
    const unsigned short* xbu = (const unsigned short*)xb;
    int act = lane < 48;
    int cb = lane * 4;

    // ---- Phase A: gather M' (and stage x rows), 4 nodes per wave ----
    for (int nl = wave * 4; nl < wave * 4 + 4; nl++) {
        int node = node0 + nl;
        int d = deg[node]; if (d > CAP) d = CAP;
        d = __builtin_amdgcn_readfirstlane(d);   // wave-uniform loop bound
        int nbrval = 0;
        if (lane < d) nbrval = slots[(node << 6) + lane];
        ushort4 xv = {0, 0, 0, 0};
        if (act) xv = *(const ushort4*)&xbu[node * Cch + cb];
        float m0 = -INFINITY, m1 = -INFINITY, m2 = -INFINITY, m3 = -INFINITY;
        int k = 0;
        for (; k + 8 <= d; k += 8) {
            int s[8];
#pragma unroll
            for (int u = 0; u < 8; u++) s[u] = __builtin_amdgcn_readlane(nbrval, k + u);
            if (act) {
                ushort4 v[8];
#pragma unroll
                for (int u = 0; u < 8; u++) v[u] = *(const ushort4*)&xbu[s[u] * Cch + cb];
                RED8(m0, x); RED8(m1, y); RED8(m2, z); RED8(m3, w);
            }
        }
        if (k + 4 <= d) {
            int s0 = __builtin_amdgcn_readlane(nbrval, k);
            int s1 = __builtin_amdgcn_readlane(nbrval, k + 1);
            int s2 = __builtin_amdgcn_readlane(nbrval, k + 2);
            int s3 = __builtin_amdgcn_readlane(nbrval, k + 3);
            if (act) {
                ushort4 v0 = *(const ushort4*)&xbu[s0 * Cch + cb];
                ushort4 v1 = *(const ushort4*)&xbu[s1 * Cch + cb];
                ushort4 v2 = *(const ushort4*)&xbu[s2 * Cch + cb];
                ushort4 v3 = *(const ushort4*)&xbu[s3 * Cch + cb];
                m0 = fmaxf(m0, fmaxf(fmaxf(b2f(v0.x), b2f(v1.x)), fmaxf(b2f(v2.x), b2f(v3.x))));
                m1 = fmaxf(m1, fmaxf(fmaxf(b2f(v0.y), b2f(v1.y)), fmaxf(b2f(v2.y), b2f(v3.y))));
                m2 = fmaxf(m2, fmaxf(fmaxf(b2f(v0.z), b2f(v1.z)), fmaxf(b2f(v2.z), b2f(v3.z))));
                m3 = fmaxf(m3, fmaxf(fmaxf(b2f(v0.w), b2f(v1.w)), fmaxf(b2f(v2.w), b2f(v3.w))));
            }
            k += 4;
        }
        for (; k < d; k++) {
            int s = __builtin_amdgcn_readlane(nbrval, k);
            if (act) {
                ushort4 v = *(const ushort4*)&xbu[s * Cch + cb];
                m0 = fmaxf(m0, b2f(v.x)); m1 = fmaxf(m1, b2f(v.y));
                m2 = fmaxf(m2, b2f(v.z)); m3 = fmaxf(m3, b2f(v.w));
            }
        }
        if (act) {
            *(ushort4*)&Xs[nl * MSTR + cb] = xv;
            ushort4 o4;
            if (d > 0) {                      // wave-uniform branch
                o4.x = f2b(m0); o4.y = f2b(m1); o4.z = f2b(m2); o4.w = f2b(m3);
            } else {                          // empty segment: M' = x (cancels)
                o4 = xv;
            }
            *(ushort4*)&Ms[nl * MSTR + cb] = o4;
        }
    }
    __syncthreads();

    // ---- Phase B: K-loop, no barriers, 1-step W prefetch ----
    floatx4 acc00 = {}, acc01 = {}, acc02 = {}, acc10 = {}, acc11 = {}, acc12 = {};
    const unsigned short* Wx16 = (const unsigned short*)Wxa;
    const unsigned short* Wa16 = (const unsigned short*)Wa;
    size_t w0 = (size_t)(wave * 48 +  0 + lrow) * Cch;
    size_t w1 = (size_t)(wave * 48 + 16 + lrow) * Cch;
    size_t w2 = (size_t)(wave * 48 + 32 + lrow) * Cch;
    int kq = quad * 8;

    short8 b0 = *(const short8*)&Wx16[w0 + kq];
    short8 b1 = *(const short8*)&Wx16[w1 + kq];
    short8 b2 = *(const short8*)&Wx16[w2 + kq];
#pragma unroll
    for (int s = 0; s < 12; s++) {
        short8 n0, n1, n2;
        if (s < 11) {
            int sn = s + 1;
            const unsigned short* Wn = (sn >= 6) ? Wa16 : Wx16;
            int kkn = ((sn >= 6) ? sn - 6 : sn) * 32 + kq;
            n0 = *(const short8*)&Wn[w0 + kkn];
            n1 = *(const short8*)&Wn[w1 + kkn];
            n2 = *(const short8*)&Wn[w2 + kkn];
        }
        int kk = ((s >= 6) ? s - 6 : s) * 32 + kq;
        const unsigned short* Ar = (s >= 6) ? Ms : Xs;
        short8 af0 = *(const short8*)&Ar[lrow * MSTR + kk];
        short8 af1 = *(const short8*)&Ar[(16 + lrow) * MSTR + kk];
        MFMA6();
        if (s < 11) { b0 = n0; b1 = n1; b2 = n2; }
    }

    // ---- Epilogue. D layout: col(lane&15)=node, row(quad*4+r)=o ----
    floatx4 accs[2][3] = {{acc00, acc01, acc02}, {acc10, acc11, acc12}};
#pragma unroll
    for (int i = 0; i < 2; i++) {
        int node = node0 + i * 16 + lrow;
        int b = node >> 12, n = node & 4095;
#pragma unroll
        for (int j = 0; j < 3; j++) {
            int ob = wave * 48 + j * 16 + quad * 4;
#pragma unroll
            for (int r = 0; r < 4; r++) {
                int o = ob + r;
                float v = accs[i][j][r] + bias[o];
                out[((size_t)(b * COUT + o)) * Nn + n] = fmaxf(v, 0.0f);
            }
        }
    }
}

// ---------------------------------------------------------------------------
extern "C" void kernel_launch(void* const* d_in, const int* in_sizes, int n_in,
                              void* d_out, int out_size, void* d_ws, size_t ws_size,
                              hipStream_t stream) {
    const float* x    = (const float*)d_in[0];
    const int*   ew   = (const int*)d_in[1];
    const float* W    = (const float*)d_in[2];
    const float* bias = (const float*)d_in[3];
    float* out        = (float*)d_out;

    char* ws = (char*)d_ws;
    __hip_bfloat16* xb   = (__hip_bfloat16*)ws;                       // 6291456 B
    __hip_bfloat16* Wxa  = (__hip_bfloat16*)(ws + 12582912);          // 147456 B
    __hip_bfloat16* Wa   = (__hip_bfloat16*)(ws + 12730368);          // 147456 B
    int* deg   = (int*)(ws + 12877824);                               // 65536 B
    int* slots = (int*)(ws + 12943360);                               // 4194304 B
    int* flag  = (int*)(ws + 17137664);                               // 4 B

    prep_kernel<<<3425, 256, 0, stream>>>(x, (const unsigned int*)ew, W, xb, Wxa, Wa, deg, flag);
    fill_kernel<<<Ecnt / 512, 256, 0, stream>>>(ew, flag, deg, slots);
    p2_kernel<<<BN / 32, 512, 0, stream>>>(deg, slots, xb, Wxa, Wa, bias, out);
}